// Round 3
// baseline (1910.770 us; speedup 1.0000x reference)
//
#include <hip/hip_runtime.h>

#define N_NODES 20000
#define N_EDGES 320000
#define R_RUNS 10
#define HID 64
#define NG 128
#define NC 10
#define NL 4
#define MROWS (R_RUNS * N_NODES)   // 200000
#define BN_EPS 1e-5f

typedef __bf16 bf16;
typedef __attribute__((ext_vector_type(8))) __bf16 bf16x8;
typedef __attribute__((ext_vector_type(4))) float f32x4;

// ---------------- workspace layout (bytes) — smalls first, big buffers last
constexpr size_t OFF_FFLAG   = 0;          // int: 1 = floats are f32, 0 = bf16
constexpr size_t OFF_MFLAG   = 8;          // int: mask elem width 1/2/4
constexpr size_t OFF_SUMS    = 256;        // f32[64]
constexpr size_t OFF_SQS     = 512;        // f32[64]
constexpr size_t OFF_SCALE   = 768;        // f32[64]
constexpr size_t OFF_SHIFT   = 1024;       // f32[64]
constexpr size_t OFF_POOLED  = 1280;       // f32[128*64] -> 34048
constexpr size_t OFF_OUTACC  = 34048;      // f32[1280] -> 39168 pad 39424
constexpr size_t OFF_ROWST   = 39424;      // int[20001] -> pad 80384
constexpr size_t OFF_CURSOR  = 119808;     // int[20001] -> pad 80384
constexpr size_t OFF_COL     = 200192;     // int[320000] -> 1480192 pad
constexpr size_t OFF_PARAMS  = 1480704;    // bf16[37554] -> pad 75264
constexpr size_t OFF_XB      = 1555968;    // bf16[1280000] = 2,560,000
constexpr size_t OFF_H       = 4115968;    // bf16[12.8M] = 25,600,000
constexpr size_t OFF_Z       = 29715968;   // bf16[12.8M] = 25,600,000
// end = 55,315,968 (~52.8 MB)

// params block element offsets
#define PW1  0        // conv_w1: 4*64*64
#define PB1  16384    // conv_b1: 4*64
#define PG1  16640    // bn1_g
#define PBB1 16896    // bn1_b
#define PW2  17152    // conv_w2: 4*64*64
#define PB2  33536    // conv_b2
#define PG2  33792    // bn_g
#define PBB2 34048    // bn_b
#define PFW  34304    // fc_w: 5*64*10
#define PFB  37504    // fc_b: 5*10
#define PTOT 37554
#define CVT_TOT (1280000 + PTOT)

// ---------------- runtime dtype detection ----------------
// fflag: x as uint16 — even-index halfwords of f32 data are random mantissa
// bits (~40% have bf16-exponent >= 0x90); bf16 N(0,1) data has none.
// mflag: mask word patterns — low-half 0x3F80 => bf16(w=2); word==0x3F800000
// => f32(w=4, same reader as int32); word>1 otherwise => uint8(w=1); else int32(w=4).
__global__ void detect_kernel(const unsigned short* __restrict__ xu,
                              const unsigned int* __restrict__ mw,
                              int* fflag, int* mflag) {
    __shared__ int s_insane, s_low, s_f32w, s_gt1;
    int tid = threadIdx.x;
    if (tid == 0) { s_insane = 0; s_low = 0; s_f32w = 0; s_gt1 = 0; }
    __syncthreads();
    int insane = 0, lowp = 0, f32w = 0, gt1 = 0;
    for (int i = tid; i < 4096; i += 256) {
        unsigned int u = xu[2 * i];
        unsigned int e = (u >> 7) & 0xFFu;
        if (e >= 0x90u) insane++;
    }
    for (int i = tid; i < 50000; i += 256) {
        unsigned int w = mw[i];
        if ((w & 0xFFFFu) == 0x3F80u) lowp = 1;
        if (w == 0x3F800000u) f32w = 1;
        if (w > 1u && w != 0x3F800000u && (w & 0xFFFFu) != 0x3F80u) gt1 = 1;
    }
    if (insane) atomicAdd(&s_insane, insane);
    if (lowp)   atomicOr(&s_low, 1);
    if (f32w)   atomicOr(&s_f32w, 1);
    if (gt1)    atomicOr(&s_gt1, 1);
    __syncthreads();
    if (tid == 0) {
        *fflag = (s_insane > 64) ? 1 : 0;
        *mflag = s_low ? 2 : (s_f32w ? 4 : (s_gt1 ? 1 : 4));
    }
}

// ---------------- convert all float inputs to canonical bf16 ----------------
__device__ inline bf16 ld_any(const void* p, int i, int f32mode) {
    if (f32mode) return (bf16)((const float*)p)[i];
    return ((const bf16*)p)[i];
}

__global__ void convert_kernel(const int* __restrict__ fflag,
                               const void* x, const void* w1, const void* b1,
                               const void* g1, const void* bb1, const void* w2,
                               const void* b2, const void* g2, const void* bb2,
                               const void* fw, const void* fb,
                               bf16* __restrict__ xb, bf16* __restrict__ params) {
    int t = blockIdx.x * 256 + threadIdx.x;
    if (t >= CVT_TOT) return;
    int f = *fflag;
    if (t < 1280000) { xb[t] = ld_any(x, t, f); return; }
    int u = t - 1280000;
    const void* src; int base;
    if      (u < PB1)  { src = w1;  base = PW1; }
    else if (u < PG1)  { src = b1;  base = PB1; }
    else if (u < PBB1) { src = g1;  base = PG1; }
    else if (u < PW2)  { src = bb1; base = PBB1; }
    else if (u < PB2)  { src = w2;  base = PW2; }
    else if (u < PG2)  { src = b2;  base = PB2; }
    else if (u < PBB2) { src = g2;  base = PG2; }
    else if (u < PFW)  { src = bb2; base = PBB2; }
    else if (u < PFB)  { src = fw;  base = PFW; }
    else               { src = fb;  base = PFB; }
    params[u] = ld_any(src, u - base, f);
}

// h0[r,n,f] = drop ? 0 : x[n,f]
__global__ void build_h0_kernel(const bf16* __restrict__ xb, const void* __restrict__ maskp,
                                const int* __restrict__ mflag, bf16* __restrict__ h) {
    int r = blockIdx.y;
    int i = blockIdx.x * 256 + threadIdx.x;     // 0 .. 20000*8-1
    int n = i >> 3;
    int f0 = (i & 7) * 8;
    size_t idx = (size_t)r * N_NODES + n;
    int w = *mflag;
    int dropped;
    if (w == 1)      dropped = ((const unsigned char*)maskp)[idx] != 0;
    else if (w == 2) dropped = ((const unsigned short*)maskp)[idx] != 0;
    else             dropped = ((const unsigned int*)maskp)[idx] != 0;
    bf16x8 v;
    if (dropped) {
        #pragma unroll
        for (int j = 0; j < 8; ++j) v[j] = (bf16)0.0f;
    } else {
        v = *(const bf16x8*)(xb + (size_t)n * HID + f0);
    }
    *(bf16x8*)(h + ((size_t)r * N_NODES + n) * HID + f0) = v;
}

// ---------------- CSR build (keyed by dst) ----------------
__global__ void csr_count_kernel(const int* __restrict__ ei, int* __restrict__ deg) {
    int e = blockIdx.x * 256 + threadIdx.x;
    if (e < N_EDGES) atomicAdd(&deg[ei[N_EDGES + e]], 1);
}

__global__ void csr_scan_kernel(int* __restrict__ deg /*in: degree, out: cursor*/,
                                int* __restrict__ row_start) {
    __shared__ int lds[1024];
    int tid = threadIdx.x;
    const int CH = 20;                 // 1024*20 = 20480 >= 20000
    int base = tid * CH;
    int local[CH];
    int s = 0;
    #pragma unroll
    for (int j = 0; j < CH; ++j) {
        int n = base + j;
        int d = (n < N_NODES) ? deg[n] : 0;
        local[j] = d; s += d;
    }
    lds[tid] = s; __syncthreads();
    for (int off = 1; off < 1024; off <<= 1) {
        int add = (tid >= off) ? lds[tid - off] : 0;
        __syncthreads();
        lds[tid] += add;
        __syncthreads();
    }
    int excl = lds[tid] - s;
    #pragma unroll
    for (int j = 0; j < CH; ++j) {
        int n = base + j;
        if (n < N_NODES) { row_start[n] = excl; deg[n] = excl; excl += local[j]; }
    }
    if (tid == 1023) row_start[N_NODES] = lds[1023];
}

__global__ void csr_fill_kernel(const int* __restrict__ ei, int* __restrict__ cursor,
                                int* __restrict__ col) {
    int e = blockIdx.x * 256 + threadIdx.x;
    if (e < N_EDGES) {
        int src = ei[e];
        int dst = ei[N_EDGES + e];
        int pos = atomicAdd(&cursor[dst], 1);
        col[pos] = src;
    }
}

// ---------------- aggregation: z[r,n,:] = h[r,n,:] + sum_{e: dst=n} h[r,src,:]
__global__ void agg_kernel(const bf16* __restrict__ h, const int* __restrict__ row_start,
                           const int* __restrict__ col, bf16* __restrict__ z) {
    int lane = threadIdx.x & 63;
    int n = blockIdx.x * 4 + (threadIdx.x >> 6);
    int r = blockIdx.y;
    const bf16* hr = h + (size_t)r * N_NODES * HID;
    float acc = (float)hr[(size_t)n * HID + lane];
    int beg = row_start[n], end = row_start[n + 1];
    for (int idx = beg; idx < end; ++idx) {
        int s = col[idx];
        acc += (float)hr[(size_t)s * HID + lane];
    }
    z[((size_t)r * N_NODES + n) * HID + lane] = (bf16)acc;
}

// ---------------- GEMM: out[M,64] = in[M,64] @ W[64,64] + bias  (bf16, fp32 acc)
// MFMA 16x16x32 bf16 maps (m89/m91-verified):
//   A: m=lane&15, k=(lane>>4)*8+j ; B: n=lane&15, k=(lane>>4)*8+j
//   C/D: col=lane&15, row=(lane>>4)*4+reg
// in/out may alias: each wave reads+writes only its own 16-row slice, and all
// A-loads complete (MFMA data dep) before any store.
__global__ __launch_bounds__(256) void gemm64_kernel(const bf16* in,
                                                     const bf16* __restrict__ W,
                                                     const bf16* __restrict__ bias,
                                                     bf16* out) {
    int wave = threadIdx.x >> 6;
    int lane = threadIdx.x & 63;
    int l16 = lane & 15;
    int quad = lane >> 4;
    size_t rowBase = (size_t)blockIdx.x * 64 + wave * 16;

    bf16x8 bfrag[4][2];
    #pragma unroll
    for (int nt = 0; nt < 4; ++nt) {
        int nn = nt * 16 + l16;
        #pragma unroll
        for (int c = 0; c < 2; ++c) {
            int k0 = c * 32 + quad * 8;
            bf16x8 v;
            #pragma unroll
            for (int j = 0; j < 8; ++j) v[j] = W[(size_t)(k0 + j) * HID + nn];
            bfrag[nt][c] = v;
        }
    }

    f32x4 acc[4];
    #pragma unroll
    for (int nt = 0; nt < 4; ++nt) {
        float bv = (float)bias[nt * 16 + l16];
        acc[nt] = (f32x4){bv, bv, bv, bv};
    }

    size_t row = rowBase + l16;
    bf16x8 afrag[2];
    #pragma unroll
    for (int c = 0; c < 2; ++c) {
        int k0 = c * 32 + quad * 8;
        afrag[c] = *(const bf16x8*)(in + row * HID + k0);
    }

    #pragma unroll
    for (int nt = 0; nt < 4; ++nt) {
        acc[nt] = __builtin_amdgcn_mfma_f32_16x16x32_bf16(afrag[0], bfrag[nt][0], acc[nt], 0, 0, 0);
        acc[nt] = __builtin_amdgcn_mfma_f32_16x16x32_bf16(afrag[1], bfrag[nt][1], acc[nt], 0, 0, 0);
    }

    #pragma unroll
    for (int nt = 0; nt < 4; ++nt) {
        #pragma unroll
        for (int reg = 0; reg < 4; ++reg) {
            size_t orow = rowBase + quad * 4 + reg;
            out[orow * HID + nt * 16 + l16] = (bf16)acc[nt][reg];
        }
    }
}

// ---------------- BN stats: per-column sum & sumsq over all MROWS rows
__global__ void stats_kernel(const bf16* __restrict__ t, float* __restrict__ sums,
                             float* __restrict__ sqs) {
    __shared__ float ls[256], lq[256];
    int tid = threadIdx.x;
    int colx = tid & 63, rg = tid >> 6;
    const int RPB = (MROWS + 255) / 256;   // 782
    int r0 = blockIdx.x * RPB;
    int r1 = min(r0 + RPB, MROWS);
    float s = 0.f, q = 0.f;
    for (int r = r0 + rg; r < r1; r += 4) {
        float v = (float)t[(size_t)r * HID + colx];
        s += v; q += v * v;
    }
    ls[tid] = s; lq[tid] = q; __syncthreads();
    if (tid < 64) {
        s = ls[tid] + ls[tid + 64] + ls[tid + 128] + ls[tid + 192];
        q = lq[tid] + lq[tid + 64] + lq[tid + 128] + lq[tid + 192];
        atomicAdd(&sums[tid], s);
        atomicAdd(&sqs[tid], q);
    }
}

__global__ void bn_finalize_kernel(const float* __restrict__ sums, const float* __restrict__ sqs,
                                   const bf16* __restrict__ g, const bf16* __restrict__ b,
                                   float* __restrict__ scale, float* __restrict__ shift) {
    int c = threadIdx.x;
    if (c < HID) {
        float mu = sums[c] * (1.0f / MROWS);
        float var = sqs[c] * (1.0f / MROWS) - mu * mu;
        float rs = rsqrtf(var + BN_EPS);
        float a = (float)g[c] * rs;
        scale[c] = a;
        shift[c] = (float)b[c] - mu * a;
    }
}

// o = relu(t * scale[col] + shift[col]); t and o may alias (thread-local)
__global__ void bn_relu_kernel(const bf16* t, const float* __restrict__ scale,
                               const float* __restrict__ shift, bf16* o) {
    int tid = blockIdx.x * 256 + threadIdx.x;    // 1.6M threads
    size_t off = (size_t)tid * 8;
    int k0 = (int)(off & 63);
    bf16x8 v = *(const bf16x8*)(t + off);
    f32x4 s0 = *(const f32x4*)(scale + k0);
    f32x4 s1 = *(const f32x4*)(scale + k0 + 4);
    f32x4 h0 = *(const f32x4*)(shift + k0);
    f32x4 h1 = *(const f32x4*)(shift + k0 + 4);
    bf16x8 o8;
    #pragma unroll
    for (int j = 0; j < 4; ++j)
        o8[j] = (bf16)fmaxf((float)v[j] * s0[j] + h0[j], 0.f);
    #pragma unroll
    for (int j = 4; j < 8; ++j)
        o8[j] = (bf16)fmaxf((float)v[j] * s1[j - 4] + h1[j - 4], 0.f);
    *(bf16x8*)(o + off) = o8;
}

// pooled[g,f] += (1/R) * sum_r h[r,n,f]   for batch[n]==g
__global__ void pool_kernel(const bf16* __restrict__ h, const int* __restrict__ batch,
                            float* __restrict__ pooled) {
    int gid = blockIdx.x * 256 + threadIdx.x;  // 0 .. 20000*64-1
    int f = gid & 63, n = gid >> 6;
    float s = 0.f;
    #pragma unroll
    for (int r = 0; r < R_RUNS; ++r)
        s += (float)h[((size_t)r * N_NODES + n) * HID + f];
    atomicAdd(&pooled[batch[n] * HID + f], s * (1.0f / R_RUNS));
}

// outacc[g,c] += pooled[g,:] @ fcw[:,c] + fcb[c]
__global__ void fc_kernel(const float* __restrict__ pooled, const bf16* __restrict__ fcw,
                          const bf16* __restrict__ fcb, float* __restrict__ outacc) {
    int tid = blockIdx.x * 256 + threadIdx.x;
    if (tid >= NG * NC) return;
    int g = tid / NC, c = tid % NC;
    float s = (float)fcb[c];
    for (int k = 0; k < HID; ++k)
        s += pooled[g * HID + k] * (float)fcw[k * NC + c];
    outacc[tid] += s;
}

__global__ void logsoftmax_kernel(const float* __restrict__ outacc,
                                  const int* __restrict__ fflag, void* __restrict__ out) {
    int g = threadIdx.x;
    if (g >= NG) return;
    float v[NC];
    float m = -1e30f;
    #pragma unroll
    for (int c = 0; c < NC; ++c) { v[c] = outacc[g * NC + c]; m = fmaxf(m, v[c]); }
    float s = 0.f;
    #pragma unroll
    for (int c = 0; c < NC; ++c) s += expf(v[c] - m);
    float lg = logf(s);
    int f = *fflag;
    #pragma unroll
    for (int c = 0; c < NC; ++c) {
        float val = v[c] - m - lg;
        if (f) ((float*)out)[g * NC + c] = val;
        else   ((bf16*)out)[g * NC + c] = (bf16)val;
    }
}

extern "C" void kernel_launch(void* const* d_in, const int* in_sizes, int n_in,
                              void* d_out, int out_size, void* d_ws, size_t ws_size,
                              hipStream_t stream) {
    const void* x       = d_in[0];
    const int*  ei      = (const int*)d_in[1];
    const int*  batch   = (const int*)d_in[2];
    const void* maskp   = d_in[3];

    char* ws = (char*)d_ws;
    int*   fflag   = (int*)(ws + OFF_FFLAG);
    int*   mflag   = (int*)(ws + OFF_MFLAG);
    float* sums    = (float*)(ws + OFF_SUMS);
    float* sqs     = (float*)(ws + OFF_SQS);
    float* scalep  = (float*)(ws + OFF_SCALE);
    float* shiftp  = (float*)(ws + OFF_SHIFT);
    float* pooled  = (float*)(ws + OFF_POOLED);
    float* outacc  = (float*)(ws + OFF_OUTACC);
    int*   rowst   = (int*)(ws + OFF_ROWST);
    int*   cursor  = (int*)(ws + OFF_CURSOR);
    int*   colbuf  = (int*)(ws + OFF_COL);
    bf16*  params  = (bf16*)(ws + OFF_PARAMS);
    bf16*  xb      = (bf16*)(ws + OFF_XB);
    bf16*  h       = (bf16*)(ws + OFF_H);
    bf16*  z       = (bf16*)(ws + OFF_Z);

    hipMemsetAsync(ws, 0, 256, stream);                      // flags
    hipMemsetAsync(outacc, 0, NG * NC * 4, stream);
    hipMemsetAsync(cursor, 0, (N_NODES + 1) * 4, stream);

    detect_kernel<<<1, 256, 0, stream>>>((const unsigned short*)x, (const unsigned int*)maskp,
                                         fflag, mflag);
    convert_kernel<<<(CVT_TOT + 255) / 256, 256, 0, stream>>>(
        fflag, x, d_in[4], d_in[5], d_in[6], d_in[7], d_in[8], d_in[9], d_in[10],
        d_in[11], d_in[12], d_in[13], xb, params);

    build_h0_kernel<<<dim3(625, R_RUNS), 256, 0, stream>>>(xb, maskp, mflag, h);

    csr_count_kernel<<<(N_EDGES + 255) / 256, 256, 0, stream>>>(ei, cursor);
    csr_scan_kernel<<<1, 1024, 0, stream>>>(cursor, rowst);
    csr_fill_kernel<<<(N_EDGES + 255) / 256, 256, 0, stream>>>(ei, cursor, colbuf);

    // level 0 pool + fc
    hipMemsetAsync(pooled, 0, NG * HID * 4, stream);
    pool_kernel<<<(N_NODES * HID) / 256, 256, 0, stream>>>(h, batch, pooled);
    fc_kernel<<<5, 256, 0, stream>>>(pooled, params + PFW, params + PFB, outacc);

    for (int i = 0; i < NL; ++i) {
        agg_kernel<<<dim3(N_NODES / 4, R_RUNS), 256, 0, stream>>>(h, rowst, colbuf, z);

        gemm64_kernel<<<MROWS / 64, 256, 0, stream>>>(z, params + PW1 + i * 4096,
                                                      params + PB1 + i * 64, z);  // in-place
        hipMemsetAsync(sums, 0, 512, stream);  // sums + sqs contiguous
        stats_kernel<<<256, 256, 0, stream>>>(z, sums, sqs);
        bn_finalize_kernel<<<1, 64, 0, stream>>>(sums, sqs, params + PG1 + i * 64,
                                                 params + PBB1 + i * 64, scalep, shiftp);
        bn_relu_kernel<<<(MROWS * HID / 8) / 256, 256, 0, stream>>>(z, scalep, shiftp, z);

        gemm64_kernel<<<MROWS / 64, 256, 0, stream>>>(z, params + PW2 + i * 4096,
                                                      params + PB2 + i * 64, z);  // in-place
        hipMemsetAsync(sums, 0, 512, stream);
        stats_kernel<<<256, 256, 0, stream>>>(z, sums, sqs);
        bn_finalize_kernel<<<1, 64, 0, stream>>>(sums, sqs, params + PG2 + i * 64,
                                                 params + PBB2 + i * 64, scalep, shiftp);
        bn_relu_kernel<<<(MROWS * HID / 8) / 256, 256, 0, stream>>>(z, scalep, shiftp, h);

        hipMemsetAsync(pooled, 0, NG * HID * 4, stream);
        pool_kernel<<<(N_NODES * HID) / 256, 256, 0, stream>>>(h, batch, pooled);
        fc_kernel<<<5, 256, 0, stream>>>(pooled, params + PFW + (i + 1) * 640,
                                         params + PFB + (i + 1) * 10, outacc);
    }

    logsoftmax_kernel<<<1, NG, 0, stream>>>(outacc, fflag, d_out);
}

// Round 4
// 982.477 us; speedup vs baseline: 1.9448x; 1.9448x over previous
//
#include <hip/hip_runtime.h>

#define N_NODES 20000
#define N_EDGES 320000
#define R_RUNS 10
#define HID 64
#define NG 128
#define NC 10
#define NL 4
#define MROWS (R_RUNS * N_NODES)   // 200000
#define BN_EPS 1e-5f

typedef __bf16 bf16;
typedef __attribute__((ext_vector_type(8))) __bf16 bf16x8;
typedef __attribute__((ext_vector_type(4))) float f32x4;
typedef unsigned int uint32;

// ---------------- workspace layout (bytes) — smalls first, big buffers last
// Feature layout is [n][r][f]: row = n*10 + r. Row order is irrelevant to
// GEMM/BN (row-symmetric); it makes agg gather all 10 runs of a neighbor
// from one contiguous 1280 B span, and pool's r-reduction contiguous.
constexpr size_t OFF_FFLAG   = 0;          // int: 1 = floats are f32, 0 = bf16
constexpr size_t OFF_MFLAG   = 8;          // int: mask elem width 1/2/4
constexpr size_t OFF_SCALE   = 256;        // f32[64]
constexpr size_t OFF_SHIFT   = 512;        // f32[64]
constexpr size_t OFF_STATS   = 768;        // f32[64 copies][128] = 32768 -> 33536
constexpr size_t OFF_POOLED  = 33536;      // f32[128*64] = 32768 -> 66304
constexpr size_t OFF_OUTACC  = 66304;      // f32[1280] = 5120 -> 71424 pad 71680
constexpr size_t OFF_ROWST   = 71680;      // int[20001] -> pad 80128 -> 151808
constexpr size_t OFF_CURSOR  = 151808;     // int[20001] -> 231936
constexpr size_t OFF_COL     = 231936;     // int[320000] -> 1511936
constexpr size_t OFF_PARAMS  = 1511936;    // bf16[37554] -> pad 1587200
constexpr size_t OFF_XB      = 1587200;    // bf16[1280000] -> 4147200
constexpr size_t OFF_H       = 4147200;    // bf16[12.8M] = 25,600,000
constexpr size_t OFF_Z       = 29747200;   // bf16[12.8M] = 25,600,000
// end = 55,347,200 (~52.8 MB) — fit confirmed by R3 pass

// params block element offsets
#define PW1  0
#define PB1  16384
#define PG1  16640
#define PBB1 16896
#define PW2  17152
#define PB2  33536
#define PG2  33792
#define PBB2 34048
#define PFW  34304
#define PFB  37504
#define PTOT 37554
#define CVT_TOT (1280000 + PTOT)

// ---------------- runtime dtype detection (validated in R3) ----------------
__global__ void detect_kernel(const unsigned short* __restrict__ xu,
                              const unsigned int* __restrict__ mw,
                              int* fflag, int* mflag) {
    __shared__ int s_insane, s_low, s_f32w, s_gt1;
    int tid = threadIdx.x;
    if (tid == 0) { s_insane = 0; s_low = 0; s_f32w = 0; s_gt1 = 0; }
    __syncthreads();
    int insane = 0, lowp = 0, f32w = 0, gt1 = 0;
    for (int i = tid; i < 4096; i += 256) {
        unsigned int u = xu[2 * i];
        unsigned int e = (u >> 7) & 0xFFu;
        if (e >= 0x90u) insane++;
    }
    for (int i = tid; i < 50000; i += 256) {
        unsigned int w = mw[i];
        if ((w & 0xFFFFu) == 0x3F80u) lowp = 1;
        if (w == 0x3F800000u) f32w = 1;
        if (w > 1u && w != 0x3F800000u && (w & 0xFFFFu) != 0x3F80u) gt1 = 1;
    }
    if (insane) atomicAdd(&s_insane, insane);
    if (lowp)   atomicOr(&s_low, 1);
    if (f32w)   atomicOr(&s_f32w, 1);
    if (gt1)    atomicOr(&s_gt1, 1);
    __syncthreads();
    if (tid == 0) {
        *fflag = (s_insane > 64) ? 1 : 0;
        *mflag = s_low ? 2 : (s_f32w ? 4 : (s_gt1 ? 1 : 4));
    }
}

// ---------------- convert all float inputs to canonical bf16 ----------------
__device__ inline bf16 ld_any(const void* p, int i, int f32mode) {
    if (f32mode) return (bf16)((const float*)p)[i];
    return ((const bf16*)p)[i];
}

__global__ void convert_kernel(const int* __restrict__ fflag,
                               const void* x, const void* w1, const void* b1,
                               const void* g1, const void* bb1, const void* w2,
                               const void* b2, const void* g2, const void* bb2,
                               const void* fw, const void* fb,
                               bf16* __restrict__ xb, bf16* __restrict__ params) {
    int t = blockIdx.x * 256 + threadIdx.x;
    if (t >= CVT_TOT) return;
    int f = *fflag;
    if (t < 1280000) { xb[t] = ld_any(x, t, f); return; }
    int u = t - 1280000;
    const void* src; int base;
    if      (u < PB1)  { src = w1;  base = PW1; }
    else if (u < PG1)  { src = b1;  base = PB1; }
    else if (u < PBB1) { src = g1;  base = PG1; }
    else if (u < PW2)  { src = bb1; base = PBB1; }
    else if (u < PB2)  { src = w2;  base = PW2; }
    else if (u < PG2)  { src = b2;  base = PB2; }
    else if (u < PBB2) { src = g2;  base = PG2; }
    else if (u < PFW)  { src = bb2; base = PBB2; }
    else if (u < PFB)  { src = fw;  base = PFW; }
    else               { src = fb;  base = PFB; }
    params[u] = ld_any(src, u - base, f);
}

// h0[(n*10+r)*64+f] = drop[r][n] ? 0 : x[n,f]
__global__ void build_h0_kernel(const bf16* __restrict__ xb, const void* __restrict__ maskp,
                                const int* __restrict__ mflag, bf16* __restrict__ h) {
    int i = blockIdx.x * 256 + threadIdx.x;   // (n*10+r)*8 + c ; 1.6M total
    int c = i & 7;
    int rowid = i >> 3;
    int r = rowid % R_RUNS;
    int n = rowid / R_RUNS;
    size_t midx = (size_t)r * N_NODES + n;
    int w = *mflag;
    int dropped;
    if (w == 1)      dropped = ((const unsigned char*)maskp)[midx] != 0;
    else if (w == 2) dropped = ((const unsigned short*)maskp)[midx] != 0;
    else             dropped = ((const unsigned int*)maskp)[midx] != 0;
    bf16x8 v;
    if (dropped) {
        #pragma unroll
        for (int j = 0; j < 8; ++j) v[j] = (bf16)0.0f;
    } else {
        v = *(const bf16x8*)(xb + (size_t)n * HID + c * 8);
    }
    *(bf16x8*)(h + (size_t)rowid * HID + c * 8) = v;
}

// ---------------- CSR build (keyed by dst) ----------------
__global__ void csr_count_kernel(const int* __restrict__ ei, int* __restrict__ deg) {
    int e = blockIdx.x * 256 + threadIdx.x;
    if (e < N_EDGES) atomicAdd(&deg[ei[N_EDGES + e]], 1);
}

__global__ void csr_scan_kernel(int* __restrict__ deg, int* __restrict__ row_start) {
    __shared__ int lds[1024];
    int tid = threadIdx.x;
    const int CH = 20;
    int base = tid * CH;
    int local[CH];
    int s = 0;
    #pragma unroll
    for (int j = 0; j < CH; ++j) {
        int n = base + j;
        int d = (n < N_NODES) ? deg[n] : 0;
        local[j] = d; s += d;
    }
    lds[tid] = s; __syncthreads();
    for (int off = 1; off < 1024; off <<= 1) {
        int add = (tid >= off) ? lds[tid - off] : 0;
        __syncthreads();
        lds[tid] += add;
        __syncthreads();
    }
    int excl = lds[tid] - s;
    #pragma unroll
    for (int j = 0; j < CH; ++j) {
        int n = base + j;
        if (n < N_NODES) { row_start[n] = excl; deg[n] = excl; excl += local[j]; }
    }
    if (tid == 1023) row_start[N_NODES] = lds[1023];
}

__global__ void csr_fill_kernel(const int* __restrict__ ei, int* __restrict__ cursor,
                                int* __restrict__ col) {
    int e = blockIdx.x * 256 + threadIdx.x;
    if (e < N_EDGES) {
        int src = ei[e];
        int dst = ei[N_EDGES + e];
        int pos = atomicAdd(&cursor[dst], 1);
        col[pos] = src;
    }
}

// ---------------- aggregation, one wave per NODE, all 10 runs at once.
// Node data = 1280 B = 5 chunks of 256 B; lane loads dword (2 packed bf16).
// acc[c].x = low halfword (feat 2*(lane&31)), .y = high halfword.
__global__ __launch_bounds__(256) void agg_kernel(const uint32* __restrict__ hD,
                                                  const int* __restrict__ row_start,
                                                  const int* __restrict__ col,
                                                  uint32* __restrict__ zD) {
    int lane = threadIdx.x & 63;
    int n = blockIdx.x * 4 + (threadIdx.x >> 6);
    const int NODE_DW = R_RUNS * HID / 2;   // 320
    size_t base = (size_t)n * NODE_DW + lane;
    float2 acc[5];
    #pragma unroll
    for (int c = 0; c < 5; ++c) {
        uint32 u = hD[base + c * 64];
        acc[c].x = __uint_as_float(u << 16);
        acc[c].y = __uint_as_float(u & 0xFFFF0000u);
    }
    int beg = row_start[n], end = row_start[n + 1];
    int idx = beg;
    for (; idx + 2 <= end; idx += 2) {
        int s0 = col[idx], s1 = col[idx + 1];
        size_t b0 = (size_t)s0 * NODE_DW + lane;
        size_t b1 = (size_t)s1 * NODE_DW + lane;
        uint32 u0[5], u1[5];
        #pragma unroll
        for (int c = 0; c < 5; ++c) u0[c] = hD[b0 + c * 64];
        #pragma unroll
        for (int c = 0; c < 5; ++c) u1[c] = hD[b1 + c * 64];
        #pragma unroll
        for (int c = 0; c < 5; ++c) {
            acc[c].x += __uint_as_float(u0[c] << 16) + __uint_as_float(u1[c] << 16);
            acc[c].y += __uint_as_float(u0[c] & 0xFFFF0000u) + __uint_as_float(u1[c] & 0xFFFF0000u);
        }
    }
    if (idx < end) {
        int s0 = col[idx];
        size_t b0 = (size_t)s0 * NODE_DW + lane;
        #pragma unroll
        for (int c = 0; c < 5; ++c) {
            uint32 u = hD[b0 + c * 64];
            acc[c].x += __uint_as_float(u << 16);
            acc[c].y += __uint_as_float(u & 0xFFFF0000u);
        }
    }
    #pragma unroll
    for (int c = 0; c < 5; ++c) {
        unsigned short lo = __builtin_bit_cast(unsigned short, (bf16)acc[c].x);
        unsigned short hi = __builtin_bit_cast(unsigned short, (bf16)acc[c].y);
        zD[base + c * 64] = (uint32)lo | ((uint32)hi << 16);
    }
}

// ---------------- fused GEMM: out = [bn_relu?](in) @ W + bias, + output stats
// MFMA 16x16x32 bf16 maps (m89/m91-verified):
//   A: m=lane&15, k=(lane>>4)*8+j ; B: n=lane&15, k=(lane>>4)*8+j
//   C/D: col=lane&15, row=(lane>>4)*4+reg
// in/out may alias: each wave reads/writes only its own 16-row slice.
// statsOut: float[64 copies][128] (cols 0-63 = sums, 64-127 = sumsq), must be
// zeroed before first use; bn_finalize re-zeroes after consuming.
__global__ __launch_bounds__(256) void gemm64_kernel(const bf16* in,
                                                     const bf16* __restrict__ W,
                                                     const bf16* __restrict__ bias,
                                                     bf16* out,
                                                     const float* __restrict__ scaleIn,
                                                     const float* __restrict__ shiftIn,
                                                     int apply_bn,
                                                     float* __restrict__ statsOut) {
    __shared__ float lsum[64], lsq[64];
    int tid = threadIdx.x;
    if (tid < 64) { lsum[tid] = 0.f; lsq[tid] = 0.f; }
    int wave = tid >> 6;
    int lane = tid & 63;
    int l16 = lane & 15;
    int quad = lane >> 4;
    size_t rowBase = (size_t)blockIdx.x * 64 + wave * 16;

    bf16x8 bfrag[4][2];
    #pragma unroll
    for (int nt = 0; nt < 4; ++nt) {
        int nn = nt * 16 + l16;
        #pragma unroll
        for (int c = 0; c < 2; ++c) {
            int k0 = c * 32 + quad * 8;
            bf16x8 v;
            #pragma unroll
            for (int j = 0; j < 8; ++j) v[j] = W[(size_t)(k0 + j) * HID + nn];
            bfrag[nt][c] = v;
        }
    }

    f32x4 acc[4];
    #pragma unroll
    for (int nt = 0; nt < 4; ++nt) {
        float bv = (float)bias[nt * 16 + l16];
        acc[nt] = (f32x4){bv, bv, bv, bv};
    }

    size_t row = rowBase + l16;
    bf16x8 afrag[2];
    #pragma unroll
    for (int c = 0; c < 2; ++c) {
        int k0 = c * 32 + quad * 8;
        bf16x8 v = *(const bf16x8*)(in + row * HID + k0);
        if (apply_bn) {
            #pragma unroll
            for (int j = 0; j < 8; ++j) {
                float f = (float)v[j] * scaleIn[k0 + j] + shiftIn[k0 + j];
                v[j] = (bf16)fmaxf(f, 0.f);
            }
        }
        afrag[c] = v;
    }

    #pragma unroll
    for (int nt = 0; nt < 4; ++nt) {
        acc[nt] = __builtin_amdgcn_mfma_f32_16x16x32_bf16(afrag[0], bfrag[nt][0], acc[nt], 0, 0, 0);
        acc[nt] = __builtin_amdgcn_mfma_f32_16x16x32_bf16(afrag[1], bfrag[nt][1], acc[nt], 0, 0, 0);
    }

    // stores (pre-BN output t)
    #pragma unroll
    for (int nt = 0; nt < 4; ++nt) {
        #pragma unroll
        for (int reg = 0; reg < 4; ++reg) {
            size_t orow = rowBase + quad * 4 + reg;
            out[orow * HID + nt * 16 + l16] = (bf16)acc[nt][reg];
        }
    }

    // per-block column stats of t from fp32 accumulators
    __syncthreads();   // lsum/lsq zeros visible
    #pragma unroll
    for (int nt = 0; nt < 4; ++nt) {
        float s = 0.f, q = 0.f;
        #pragma unroll
        for (int reg = 0; reg < 4; ++reg) {
            float v = acc[nt][reg];
            s += v; q += v * v;
        }
        atomicAdd(&lsum[nt * 16 + l16], s);
        atomicAdd(&lsq[nt * 16 + l16], q);
    }
    __syncthreads();
    if (tid < 64) {
        int copy = blockIdx.x & 63;
        atomicAdd(&statsOut[copy * 128 + tid], lsum[tid]);
        atomicAdd(&statsOut[copy * 128 + 64 + tid], lsq[tid]);
    }
}

// reduce 64 stat copies -> scale/shift; re-zero statsP for next use
__global__ void bn_finalize_kernel(float* __restrict__ statsP,
                                   const bf16* __restrict__ g, const bf16* __restrict__ b,
                                   float* __restrict__ scale, float* __restrict__ shift) {
    __shared__ float l[128];
    int t = threadIdx.x;   // 128 threads
    float s = 0.f;
    #pragma unroll 8
    for (int k = 0; k < 64; ++k) {
        s += statsP[k * 128 + t];
        statsP[k * 128 + t] = 0.f;
    }
    l[t] = s;
    __syncthreads();
    if (t < 64) {
        float mu = l[t] * (1.0f / MROWS);
        float var = l[t + 64] * (1.0f / MROWS) - mu * mu;
        float rs = rsqrtf(var + BN_EPS);
        float a = (float)g[t] * rs;
        scale[t] = a;
        shift[t] = (float)b[t] - mu * a;
    }
}

// fused BN+ReLU + h-materialize + pool.  has_bn=0: pool raw input (level 0).
// pooled[g,f] += (1/R) * sum_r relu(bn(t[n,r,f]))  for batch[n]==g
__global__ void pool_bn_kernel(const bf16* __restrict__ t,
                               const float* __restrict__ scale,
                               const float* __restrict__ shift,
                               int has_bn, bf16* __restrict__ hOut,
                               const int* __restrict__ batch,
                               float* __restrict__ pooled) {
    int gid = blockIdx.x * 256 + threadIdx.x;  // n*64+f, 1.28M
    int f = gid & 63, n = gid >> 6;
    float sc = has_bn ? scale[f] : 1.f;
    float sh = has_bn ? shift[f] : 0.f;
    size_t base = (size_t)n * (R_RUNS * HID) + f;
    float s = 0.f;
    #pragma unroll
    for (int r = 0; r < R_RUNS; ++r) {
        float v = (float)t[base + r * HID];
        if (has_bn) {
            v = fmaxf(v * sc + sh, 0.f);
            hOut[base + r * HID] = (bf16)v;
        }
        s += v;
    }
    atomicAdd(&pooled[batch[n] * HID + f], s * (1.0f / R_RUNS));
}

// outacc[g,c] += pooled[g,:] @ fcw[:,c] + fcb[c]
__global__ void fc_kernel(const float* __restrict__ pooled, const bf16* __restrict__ fcw,
                          const bf16* __restrict__ fcb, float* __restrict__ outacc) {
    int tid = blockIdx.x * 256 + threadIdx.x;
    if (tid >= NG * NC) return;
    int g = tid / NC, c = tid % NC;
    float s = (float)fcb[c];
    for (int k = 0; k < HID; ++k)
        s += pooled[g * HID + k] * (float)fcw[k * NC + c];
    outacc[tid] += s;
}

__global__ void logsoftmax_kernel(const float* __restrict__ outacc,
                                  const int* __restrict__ fflag, void* __restrict__ out) {
    int g = threadIdx.x;
    if (g >= NG) return;
    float v[NC];
    float m = -1e30f;
    #pragma unroll
    for (int c = 0; c < NC; ++c) { v[c] = outacc[g * NC + c]; m = fmaxf(m, v[c]); }
    float s = 0.f;
    #pragma unroll
    for (int c = 0; c < NC; ++c) s += expf(v[c] - m);
    float lg = logf(s);
    int f = *fflag;
    #pragma unroll
    for (int c = 0; c < NC; ++c) {
        float val = v[c] - m - lg;
        if (f) ((float*)out)[g * NC + c] = val;
        else   ((bf16*)out)[g * NC + c] = (bf16)val;
    }
}

extern "C" void kernel_launch(void* const* d_in, const int* in_sizes, int n_in,
                              void* d_out, int out_size, void* d_ws, size_t ws_size,
                              hipStream_t stream) {
    const void* x     = d_in[0];
    const int*  ei    = (const int*)d_in[1];
    const int*  batch = (const int*)d_in[2];
    const void* maskp = d_in[3];

    char* ws = (char*)d_ws;
    int*   fflag   = (int*)(ws + OFF_FFLAG);
    int*   mflag   = (int*)(ws + OFF_MFLAG);
    float* scalep  = (float*)(ws + OFF_SCALE);
    float* shiftp  = (float*)(ws + OFF_SHIFT);
    float* statsb  = (float*)(ws + OFF_STATS);
    float* pooled  = (float*)(ws + OFF_POOLED);
    float* outacc  = (float*)(ws + OFF_OUTACC);
    int*   rowst   = (int*)(ws + OFF_ROWST);
    int*   cursor  = (int*)(ws + OFF_CURSOR);
    int*   colbuf  = (int*)(ws + OFF_COL);
    bf16*  params  = (bf16*)(ws + OFF_PARAMS);
    bf16*  xb      = (bf16*)(ws + OFF_XB);
    bf16*  h       = (bf16*)(ws + OFF_H);
    bf16*  z       = (bf16*)(ws + OFF_Z);

    hipMemsetAsync(ws, 0, 256, stream);                       // flags
    hipMemsetAsync(statsb, 0, 64 * 128 * 4, stream);
    hipMemsetAsync(outacc, 0, NG * NC * 4, stream);
    hipMemsetAsync(cursor, 0, (N_NODES + 1) * 4, stream);

    detect_kernel<<<1, 256, 0, stream>>>((const unsigned short*)x,
                                         (const unsigned int*)maskp, fflag, mflag);
    convert_kernel<<<(CVT_TOT + 255) / 256, 256, 0, stream>>>(
        fflag, x, d_in[4], d_in[5], d_in[6], d_in[7], d_in[8], d_in[9], d_in[10],
        d_in[11], d_in[12], d_in[13], xb, params);

    build_h0_kernel<<<(MROWS * 8) / 256, 256, 0, stream>>>(xb, maskp, mflag, h);

    csr_count_kernel<<<(N_EDGES + 255) / 256, 256, 0, stream>>>(ei, cursor);
    csr_scan_kernel<<<1, 1024, 0, stream>>>(cursor, rowst);
    csr_fill_kernel<<<(N_EDGES + 255) / 256, 256, 0, stream>>>(ei, cursor, colbuf);

    // level 0: pool raw h0 + fc
    hipMemsetAsync(pooled, 0, NG * HID * 4, stream);
    pool_bn_kernel<<<(N_NODES * HID) / 256, 256, 0, stream>>>(h, nullptr, nullptr, 0,
                                                              nullptr, batch, pooled);
    fc_kernel<<<5, 256, 0, stream>>>(pooled, params + PFW, params + PFB, outacc);

    for (int i = 0; i < NL; ++i) {
        agg_kernel<<<N_NODES / 4, 256, 0, stream>>>((const uint32*)h, rowst, colbuf,
                                                    (uint32*)z);

        gemm64_kernel<<<MROWS / 64, 256, 0, stream>>>(z, params + PW1 + i * 4096,
                                                      params + PB1 + i * 64, z,
                                                      nullptr, nullptr, 0, statsb);
        bn_finalize_kernel<<<1, 128, 0, stream>>>(statsb, params + PG1 + i * 64,
                                                  params + PBB1 + i * 64, scalep, shiftp);

        gemm64_kernel<<<MROWS / 64, 256, 0, stream>>>(z, params + PW2 + i * 4096,
                                                      params + PB2 + i * 64, z,
                                                      scalep, shiftp, 1, statsb);
        bn_finalize_kernel<<<1, 128, 0, stream>>>(statsb, params + PG2 + i * 64,
                                                  params + PBB2 + i * 64, scalep, shiftp);

        hipMemsetAsync(pooled, 0, NG * HID * 4, stream);
        pool_bn_kernel<<<(N_NODES * HID) / 256, 256, 0, stream>>>(z, scalep, shiftp, 1,
                                                                  h, batch, pooled);
        fc_kernel<<<5, 256, 0, stream>>>(pooled, params + PFW + (i + 1) * 640,
                                         params + PFB + (i + 1) * 10, outacc);
    }

    logsoftmax_kernel<<<1, NG, 0, stream>>>(outacc, fflag, d_out);
}

// Round 5
// 873.436 us; speedup vs baseline: 2.1876x; 1.1248x over previous
//
#include <hip/hip_runtime.h>

#define N_NODES 20000
#define N_EDGES 320000
#define R_RUNS 10
#define HID 64
#define NG 128
#define NC 10
#define NL 4
#define MROWS (R_RUNS * N_NODES)   // 200000
#define BN_EPS 1e-5f
#define NCOPY 16                   // stats copies per buffer

typedef __bf16 bf16;
typedef __attribute__((ext_vector_type(8))) __bf16 bf16x8;
typedef __attribute__((ext_vector_type(4))) float f32x4;
typedef unsigned int uint32;

// ---------------- workspace layout (bytes)
// Feature layout [n][r][f] (row = n*10+r): agg gathers a neighbor's 10 runs
// from one contiguous 1280B span; pool's r-reduction is contiguous.
// Zero region first (single memset): flags, cursor, stats, pooled5.
constexpr size_t OFF_FLAGS   = 0;          // int[4] counters, pad 256
constexpr size_t OFF_CURSOR  = 256;        // int[20001] -> pad 80384
constexpr size_t OFF_STATS   = 80384;      // f32[8 bufs][16 copies][128] = 65536
constexpr size_t OFF_POOLED5 = 145920;     // f32[5][128][64] = 163840
constexpr size_t ZERO_BYTES  = 309760;
constexpr size_t OFF_ROWST   = 309760;     // int[20001] -> pad 389888
constexpr size_t OFF_COL     = 389888;     // int[320000] -> 1669888
constexpr size_t OFF_PARAMS  = 1669888;    // bf16[37554] -> pad 1745152
constexpr size_t OFF_XB      = 1745152;    // bf16[1280000] -> 4305152
constexpr size_t OFF_H       = 4305152;    // 25,600,000
constexpr size_t OFF_Z       = 29905152;   // 25,600,000 -> end 55,505,152

// params block element offsets (w1/w2 stored PRE-SWIZZLED in B-fragment order)
#define PW1  0
#define PB1  16384
#define PG1  16640
#define PBB1 16896
#define PW2  17152
#define PB2  33536
#define PG2  33792
#define PBB2 34048
#define PFW  34304
#define PFB  37504
#define PTOT 37554
#define CVT_TOT (1280000 + PTOT)

// ---------------- runtime dtype detection (64 blocks; raw counters) --------
// cnts[0]: #x-halfwords with bf16-exponent>=0x90 (f32 data ~40%, bf16 ~0)
// cnts[1]: mask has low-half 0x3F80 (bf16 1.0)   cnts[2]: word 0x3F800000 (f32)
// cnts[3]: word>1 otherwise (packed u8)
__global__ void detect_kernel(const unsigned short* __restrict__ xu,
                              const unsigned int* __restrict__ mw,
                              int* __restrict__ cnts) {
    int tid = blockIdx.x * 256 + threadIdx.x;   // 16384 threads
    int insane = 0, lowp = 0, f32w = 0, gt1 = 0;
    for (int i = tid; i < 4096; i += 16384) {
        unsigned int u = xu[2 * i];
        if (((u >> 7) & 0xFFu) >= 0x90u) insane++;
    }
    for (int i = tid; i < 50000; i += 16384) {
        unsigned int w = mw[i];
        if ((w & 0xFFFFu) == 0x3F80u) lowp = 1;
        else if (w == 0x3F800000u) f32w = 1;
        else if (w > 1u) gt1 = 1;
    }
    if (insane) atomicAdd(&cnts[0], insane);
    if (lowp)   atomicOr(&cnts[1], 1);
    if (f32w)   atomicOr(&cnts[2], 1);
    if (gt1)    atomicOr(&cnts[3], 1);
}

__device__ inline bf16 ld_any(const void* p, int i, int f32mode) {
    if (f32mode) return (bf16)((const float*)p)[i];
    return ((const bf16*)p)[i];
}

// convert all float inputs to canonical bf16; w1/w2 are written in the exact
// per-lane B-fragment order gemm consumes:
//   Wf[((nt*2+c)*64 + lane)*8 + j] = W[(c*32+(lane>>4)*8+j)*64 + nt*16+(lane&15)]
__global__ void convert_kernel(const int* __restrict__ cnts,
                               const void* x, const void* w1, const void* b1,
                               const void* g1, const void* bb1, const void* w2,
                               const void* b2, const void* g2, const void* bb2,
                               const void* fw, const void* fb,
                               bf16* __restrict__ xb, bf16* __restrict__ params) {
    int t = blockIdx.x * 256 + threadIdx.x;
    if (t >= CVT_TOT) return;
    int f = cnts[0] > 64;
    if (t < 1280000) { xb[t] = ld_any(x, t, f); return; }
    int u = t - 1280000;
    if (u < PB1 || (u >= PW2 && u < PB2)) {       // swizzled weight regions
        const void* src = (u < PB1) ? w1 : w2;
        int v = (u < PB1) ? u : u - PW2;
        int layer = v >> 12, rem = v & 4095;
        int j = rem & 7, lane = (rem >> 3) & 63, ntc = rem >> 9;
        int nt = ntc >> 1, c = ntc & 1;
        int k = c * 32 + (lane >> 4) * 8 + j;
        int n = nt * 16 + (lane & 15);
        params[u] = ld_any(src, layer * 4096 + k * 64 + n, f);
        return;
    }
    const void* src; int base;
    if      (u < PG1)  { src = b1;  base = PB1; }
    else if (u < PBB1) { src = g1;  base = PG1; }
    else if (u < PW2)  { src = bb1; base = PBB1; }
    else if (u < PG2)  { src = b2;  base = PB2; }
    else if (u < PBB2) { src = g2;  base = PG2; }
    else if (u < PFW)  { src = bb2; base = PBB2; }
    else if (u < PFB)  { src = fw;  base = PFW; }
    else               { src = fb;  base = PFB; }
    params[u] = ld_any(src, u - base, f);
}

// h0[(n*10+r)*64+f] = drop[r][n] ? 0 : x[n,f]
__global__ void build_h0_kernel(const bf16* __restrict__ xb, const void* __restrict__ maskp,
                                const int* __restrict__ cnts, bf16* __restrict__ h) {
    int i = blockIdx.x * 256 + threadIdx.x;   // (n*10+r)*8 + c ; 1.6M total
    int c = i & 7;
    int rowid = i >> 3;
    int r = rowid % R_RUNS;
    int n = rowid / R_RUNS;
    size_t midx = (size_t)r * N_NODES + n;
    int w = cnts[1] ? 2 : (cnts[2] ? 4 : (cnts[3] ? 1 : 4));
    int dropped;
    if (w == 1)      dropped = ((const unsigned char*)maskp)[midx] != 0;
    else if (w == 2) dropped = ((const unsigned short*)maskp)[midx] != 0;
    else             dropped = ((const unsigned int*)maskp)[midx] != 0;
    bf16x8 v;
    if (dropped) {
        #pragma unroll
        for (int j = 0; j < 8; ++j) v[j] = (bf16)0.0f;
    } else {
        v = *(const bf16x8*)(xb + (size_t)n * HID + c * 8);
    }
    *(bf16x8*)(h + (size_t)rowid * HID + c * 8) = v;
}

// ---------------- CSR build (keyed by dst) ----------------
__global__ void csr_count_kernel(const int* __restrict__ ei, int* __restrict__ deg) {
    int e = blockIdx.x * 256 + threadIdx.x;
    if (e < N_EDGES) atomicAdd(&deg[ei[N_EDGES + e]], 1);
}

__global__ void csr_scan_kernel(int* __restrict__ deg, int* __restrict__ row_start) {
    __shared__ int lds[1024];
    int tid = threadIdx.x;
    const int CH = 20;
    int base = tid * CH;
    int local[CH];
    int s = 0;
    #pragma unroll
    for (int j = 0; j < CH; ++j) {
        int n = base + j;
        int d = (n < N_NODES) ? deg[n] : 0;
        local[j] = d; s += d;
    }
    lds[tid] = s; __syncthreads();
    for (int off = 1; off < 1024; off <<= 1) {
        int add = (tid >= off) ? lds[tid - off] : 0;
        __syncthreads();
        lds[tid] += add;
        __syncthreads();
    }
    int excl = lds[tid] - s;
    #pragma unroll
    for (int j = 0; j < CH; ++j) {
        int n = base + j;
        if (n < N_NODES) { row_start[n] = excl; deg[n] = excl; excl += local[j]; }
    }
    if (tid == 1023) row_start[N_NODES] = lds[1023];
}

__global__ void csr_fill_kernel(const int* __restrict__ ei, int* __restrict__ cursor,
                                int* __restrict__ col) {
    int e = blockIdx.x * 256 + threadIdx.x;
    if (e < N_EDGES) {
        int src = ei[e];
        int dst = ei[N_EDGES + e];
        int pos = atomicAdd(&cursor[dst], 1);
        col[pos] = src;
    }
}

// ---------------- aggregation: one wave per node, all 10 runs, 4-wide unroll
__global__ __launch_bounds__(256) void agg_kernel(const uint32* __restrict__ hD,
                                                  const int* __restrict__ row_start,
                                                  const int* __restrict__ col,
                                                  uint32* __restrict__ zD) {
    int lane = threadIdx.x & 63;
    int n = blockIdx.x * 4 + (threadIdx.x >> 6);
    const int NODE_DW = R_RUNS * HID / 2;   // 320
    size_t base = (size_t)n * NODE_DW + lane;
    float2 acc[5];
    #pragma unroll
    for (int c = 0; c < 5; ++c) {
        uint32 u = hD[base + c * 64];
        acc[c].x = __uint_as_float(u << 16);
        acc[c].y = __uint_as_float(u & 0xFFFF0000u);
    }
    int beg = row_start[n], end = row_start[n + 1];
    int idx = beg;
    for (; idx + 4 <= end; idx += 4) {
        size_t b0 = (size_t)col[idx]     * NODE_DW + lane;
        size_t b1 = (size_t)col[idx + 1] * NODE_DW + lane;
        size_t b2 = (size_t)col[idx + 2] * NODE_DW + lane;
        size_t b3 = (size_t)col[idx + 3] * NODE_DW + lane;
        uint32 u0[5], u1[5], u2[5], u3[5];
        #pragma unroll
        for (int c = 0; c < 5; ++c) u0[c] = hD[b0 + c * 64];
        #pragma unroll
        for (int c = 0; c < 5; ++c) u1[c] = hD[b1 + c * 64];
        #pragma unroll
        for (int c = 0; c < 5; ++c) u2[c] = hD[b2 + c * 64];
        #pragma unroll
        for (int c = 0; c < 5; ++c) u3[c] = hD[b3 + c * 64];
        #pragma unroll
        for (int c = 0; c < 5; ++c) {
            acc[c].x += __uint_as_float(u0[c] << 16) + __uint_as_float(u1[c] << 16)
                      + __uint_as_float(u2[c] << 16) + __uint_as_float(u3[c] << 16);
            acc[c].y += __uint_as_float(u0[c] & 0xFFFF0000u) + __uint_as_float(u1[c] & 0xFFFF0000u)
                      + __uint_as_float(u2[c] & 0xFFFF0000u) + __uint_as_float(u3[c] & 0xFFFF0000u);
        }
    }
    for (; idx < end; ++idx) {
        size_t b0 = (size_t)col[idx] * NODE_DW + lane;
        #pragma unroll
        for (int c = 0; c < 5; ++c) {
            uint32 u = hD[b0 + c * 64];
            acc[c].x += __uint_as_float(u << 16);
            acc[c].y += __uint_as_float(u & 0xFFFF0000u);
        }
    }
    #pragma unroll
    for (int c = 0; c < 5; ++c) {
        unsigned short lo = __builtin_bit_cast(unsigned short, (bf16)acc[c].x);
        unsigned short hi = __builtin_bit_cast(unsigned short, (bf16)acc[c].y);
        zD[base + c * 64] = (uint32)lo | ((uint32)hi << 16);
    }
}

// ---------------- fused GEMM: out = [bn_relu?](in) @ W + bias, + output stats.
// If statsIn != null: per-block reduce the 16-copy raw stats of the PREVIOUS
// gemm, derive scale/shift with gammaIn/betaIn, apply BN+ReLU to input frags.
// Wf is pre-swizzled (convert_kernel). in/out may alias (per-wave 16-row slice).
__global__ __launch_bounds__(256) void gemm64_kernel(const bf16* in,
                                                     const bf16* __restrict__ Wf,
                                                     const bf16* __restrict__ bias,
                                                     bf16* out,
                                                     const float* __restrict__ statsIn,
                                                     const bf16* __restrict__ gammaIn,
                                                     const bf16* __restrict__ betaIn,
                                                     float* __restrict__ statsOut) {
    __shared__ float lstat[128];
    __shared__ float lscale[64], lshift[64];
    __shared__ float lsum[64], lsq[64];
    int tid = threadIdx.x;
    int wave = tid >> 6, lane = tid & 63, l16 = lane & 15, quad = lane >> 4;

    if (statsIn) {
        if (tid < 128) {
            float s = 0.f;
            #pragma unroll
            for (int k = 0; k < NCOPY; ++k) s += statsIn[k * 128 + tid];
            lstat[tid] = s;
        }
    }
    if (tid < 64) { lsum[tid] = 0.f; lsq[tid] = 0.f; }
    __syncthreads();
    if (statsIn && tid < 64) {
        float mu = lstat[tid] * (1.0f / MROWS);
        float var = lstat[tid + 64] * (1.0f / MROWS) - mu * mu;
        float rs = rsqrtf(var + BN_EPS);
        float a = (float)gammaIn[tid] * rs;
        lscale[tid] = a;
        lshift[tid] = (float)betaIn[tid] - mu * a;
    }
    if (statsIn) __syncthreads();

    size_t rowBase = (size_t)blockIdx.x * 64 + wave * 16;

    bf16x8 bfrag[4][2];
    #pragma unroll
    for (int nt = 0; nt < 4; ++nt)
        #pragma unroll
        for (int c = 0; c < 2; ++c)
            bfrag[nt][c] = *(const bf16x8*)(Wf + (size_t)((nt * 2 + c) * 64 + lane) * 8);

    f32x4 acc[4];
    #pragma unroll
    for (int nt = 0; nt < 4; ++nt) {
        float bv = (float)bias[nt * 16 + l16];
        acc[nt] = (f32x4){bv, bv, bv, bv};
    }

    size_t row = rowBase + l16;
    bf16x8 afrag[2];
    #pragma unroll
    for (int c = 0; c < 2; ++c) {
        int k0 = c * 32 + quad * 8;
        bf16x8 v = *(const bf16x8*)(in + row * HID + k0);
        if (statsIn) {
            #pragma unroll
            for (int j = 0; j < 8; ++j) {
                float f = (float)v[j] * lscale[k0 + j] + lshift[k0 + j];
                v[j] = (bf16)fmaxf(f, 0.f);
            }
        }
        afrag[c] = v;
    }

    #pragma unroll
    for (int nt = 0; nt < 4; ++nt) {
        acc[nt] = __builtin_amdgcn_mfma_f32_16x16x32_bf16(afrag[0], bfrag[nt][0], acc[nt], 0, 0, 0);
        acc[nt] = __builtin_amdgcn_mfma_f32_16x16x32_bf16(afrag[1], bfrag[nt][1], acc[nt], 0, 0, 0);
    }

    #pragma unroll
    for (int nt = 0; nt < 4; ++nt)
        #pragma unroll
        for (int reg = 0; reg < 4; ++reg) {
            size_t orow = rowBase + quad * 4 + reg;
            out[orow * HID + nt * 16 + l16] = (bf16)acc[nt][reg];
        }

    // column stats of pre-BN output from fp32 accumulators
    #pragma unroll
    for (int nt = 0; nt < 4; ++nt) {
        float s = 0.f, q = 0.f;
        #pragma unroll
        for (int reg = 0; reg < 4; ++reg) { float v = acc[nt][reg]; s += v; q += v * v; }
        atomicAdd(&lsum[nt * 16 + l16], s);
        atomicAdd(&lsq[nt * 16 + l16], q);
    }
    __syncthreads();
    if (tid < 64) {
        int copy = blockIdx.x & (NCOPY - 1);
        atomicAdd(&statsOut[copy * 128 + tid], lsum[tid]);
        atomicAdd(&statsOut[copy * 128 + 64 + tid], lsq[tid]);
    }
}

// fused per-block stats reduce + BN+ReLU + h-materialize + pool.
// statsIn==null: level-0 raw pool (no BN, no hOut write).
__global__ __launch_bounds__(256) void pool_bn_kernel(const bf16* __restrict__ t,
                                                      const float* __restrict__ statsIn,
                                                      const bf16* __restrict__ gammaIn,
                                                      const bf16* __restrict__ betaIn,
                                                      bf16* __restrict__ hOut,
                                                      const int* __restrict__ batch,
                                                      float* __restrict__ pooled) {
    __shared__ float lstat[128], lscale[64], lshift[64];
    int tid = threadIdx.x;
    if (statsIn) {
        if (tid < 128) {
            float s = 0.f;
            #pragma unroll
            for (int k = 0; k < NCOPY; ++k) s += statsIn[k * 128 + tid];
            lstat[tid] = s;
        }
        __syncthreads();
        if (tid < 64) {
            float mu = lstat[tid] * (1.0f / MROWS);
            float var = lstat[tid + 64] * (1.0f / MROWS) - mu * mu;
            float rs = rsqrtf(var + BN_EPS);
            float a = (float)gammaIn[tid] * rs;
            lscale[tid] = a;
            lshift[tid] = (float)betaIn[tid] - mu * a;
        }
        __syncthreads();
    }
    int gid = blockIdx.x * 256 + tid;   // n*64+f
    int f = tid & 63, n = gid >> 6;
    float sc = statsIn ? lscale[f] : 1.f;
    float sh = statsIn ? lshift[f] : 0.f;
    size_t base = (size_t)n * (R_RUNS * HID) + f;
    float s = 0.f;
    #pragma unroll
    for (int r = 0; r < R_RUNS; ++r) {
        float v = (float)t[base + r * HID];
        if (statsIn) {
            v = fmaxf(v * sc + sh, 0.f);
            hOut[base + r * HID] = (bf16)v;
        }
        s += v;
    }
    atomicAdd(&pooled[batch[n] * HID + f], s * (1.0f / R_RUNS));
}

// final: out[g,:] = log_softmax( sum_l pooled5[l][g] @ fcw_l + fcb_l )
__global__ void fc_softmax_kernel(const float* __restrict__ pooled5,
                                  const bf16* __restrict__ params,
                                  const int* __restrict__ cnts, void* __restrict__ out) {
    int g = threadIdx.x;   // 128 threads
    if (g >= NG) return;
    float o[NC];
    #pragma unroll
    for (int c = 0; c < NC; ++c) o[c] = 0.f;
    for (int l = 0; l < NL + 1; ++l) {
        const float* pg = pooled5 + ((size_t)l * NG + g) * HID;
        const bf16* fw = params + PFW + l * (HID * NC);
        for (int k = 0; k < HID; ++k) {
            float p = pg[k];
            #pragma unroll
            for (int c = 0; c < NC; ++c) o[c] += p * (float)fw[k * NC + c];
        }
        #pragma unroll
        for (int c = 0; c < NC; ++c) o[c] += (float)params[PFB + l * NC + c];
    }
    float m = -1e30f;
    #pragma unroll
    for (int c = 0; c < NC; ++c) m = fmaxf(m, o[c]);
    float s = 0.f;
    #pragma unroll
    for (int c = 0; c < NC; ++c) s += expf(o[c] - m);
    float lg = logf(s);
    int f = cnts[0] > 64;
    #pragma unroll
    for (int c = 0; c < NC; ++c) {
        float val = o[c] - m - lg;
        if (f) ((float*)out)[g * NC + c] = val;
        else   ((bf16*)out)[g * NC + c] = (bf16)val;
    }
}

extern "C" void kernel_launch(void* const* d_in, const int* in_sizes, int n_in,
                              void* d_out, int out_size, void* d_ws, size_t ws_size,
                              hipStream_t stream) {
    const void* x     = d_in[0];
    const int*  ei    = (const int*)d_in[1];
    const int*  batch = (const int*)d_in[2];
    const void* maskp = d_in[3];

    char* ws = (char*)d_ws;
    int*   cnts    = (int*)(ws + OFF_FLAGS);
    int*   cursor  = (int*)(ws + OFF_CURSOR);
    float* statsb  = (float*)(ws + OFF_STATS);
    float* pooled5 = (float*)(ws + OFF_POOLED5);
    int*   rowst   = (int*)(ws + OFF_ROWST);
    int*   colbuf  = (int*)(ws + OFF_COL);
    bf16*  params  = (bf16*)(ws + OFF_PARAMS);
    bf16*  xb      = (bf16*)(ws + OFF_XB);
    bf16*  h       = (bf16*)(ws + OFF_H);
    bf16*  z       = (bf16*)(ws + OFF_Z);

    hipMemsetAsync(ws, 0, ZERO_BYTES, stream);   // flags+cursor+stats+pooled5

    detect_kernel<<<64, 256, 0, stream>>>((const unsigned short*)x,
                                          (const unsigned int*)maskp, cnts);
    convert_kernel<<<(CVT_TOT + 255) / 256, 256, 0, stream>>>(
        cnts, x, d_in[4], d_in[5], d_in[6], d_in[7], d_in[8], d_in[9], d_in[10],
        d_in[11], d_in[12], d_in[13], xb, params);

    build_h0_kernel<<<(MROWS * 8) / 256, 256, 0, stream>>>(xb, maskp, cnts, h);

    csr_count_kernel<<<(N_EDGES + 255) / 256, 256, 0, stream>>>(ei, cursor);
    csr_scan_kernel<<<1, 1024, 0, stream>>>(cursor, rowst);
    csr_fill_kernel<<<(N_EDGES + 255) / 256, 256, 0, stream>>>(ei, cursor, colbuf);

    // level 0: raw pool of h0
    pool_bn_kernel<<<(N_NODES * HID) / 256, 256, 0, stream>>>(
        h, nullptr, nullptr, nullptr, nullptr, batch, pooled5);

    for (int i = 0; i < NL; ++i) {
        float* st1 = statsb + (size_t)(2 * i) * (NCOPY * 128);
        float* st2 = statsb + (size_t)(2 * i + 1) * (NCOPY * 128);

        agg_kernel<<<N_NODES / 4, 256, 0, stream>>>((const uint32*)h, rowst, colbuf,
                                                    (uint32*)z);

        gemm64_kernel<<<MROWS / 64, 256, 0, stream>>>(
            z, params + PW1 + i * 4096, params + PB1 + i * 64, z,
            nullptr, nullptr, nullptr, st1);

        gemm64_kernel<<<MROWS / 64, 256, 0, stream>>>(
            z, params + PW2 + i * 4096, params + PB2 + i * 64, z,
            st1, params + PG1 + i * 64, params + PBB1 + i * 64, st2);

        pool_bn_kernel<<<(N_NODES * HID) / 256, 256, 0, stream>>>(
            z, st2, params + PG2 + i * 64, params + PBB2 + i * 64, h, batch,
            pooled5 + (size_t)(i + 1) * NG * HID);
    }

    fc_softmax_kernel<<<1, 128, 0, stream>>>(pooled5, params, cnts, d_out);
}